// Round 2
// baseline (830.730 us; speedup 1.0000x reference)
//
#include <hip/hip_runtime.h>

// entmax-1.5 along last dim, d = 1024.
// One 64-lane wave per row; 16 elements/lane in registers (4x float4).
// tau solved by Newton on f(tau) = sum max(x/2 - tau, 0)^2 = 1 (convex,
// monotone decreasing; tau0 = xmax/2 - 1 guarantees f >= 1 -> monotone
// convergence, no sort). Wave reductions via DPP (no DS ops, no lgkmcnt):
// row_shr 1/2/4/8 + row_bcast15/31 leaves the total in lane 63, readlane
// broadcasts it through an SGPR (break branch becomes scalar).

constexpr int D = 1024;
constexpr int WAVES_PER_BLOCK = 4; // 256 threads

#define F2I(x) __float_as_int(x)
#define I2F(x) __int_as_float(x)

// v += dpp_shifted(v); bound_ctrl=true zeroes invalid lanes (identity for add)
#define DPP_ADD(v, ctrl)                                                      \
    (v) += I2F(__builtin_amdgcn_update_dpp(0, F2I(v), (ctrl), 0xF, 0xF, true))

// max variant: invalid/masked lanes read old = -inf (identity for max)
#define DPP_MAX(v, ctrl)                                                      \
    (v) = fmaxf((v), I2F(__builtin_amdgcn_update_dpp(F2I(-3.4e38f), F2I(v),   \
                                                     (ctrl), 0xF, 0xF, false)))

__device__ __forceinline__ float wave_sum(float v) {
    DPP_ADD(v, 0x111); // row_shr:1
    DPP_ADD(v, 0x112); // row_shr:2
    DPP_ADD(v, 0x114); // row_shr:4
    DPP_ADD(v, 0x118); // row_shr:8   -> lane 15 of each row16 = row sum
    DPP_ADD(v, 0x142); // row_bcast15 -> lane 31 = rows0+1, lane 63 = rows2+3
    DPP_ADD(v, 0x143); // row_bcast31 -> lane 63 = total
    return I2F(__builtin_amdgcn_readlane(F2I(v), 63)); // SGPR-uniform
}

__device__ __forceinline__ float wave_max(float v) {
    DPP_MAX(v, 0x111);
    DPP_MAX(v, 0x112);
    DPP_MAX(v, 0x114);
    DPP_MAX(v, 0x118);
    DPP_MAX(v, 0x142);
    DPP_MAX(v, 0x143);
    return I2F(__builtin_amdgcn_readlane(F2I(v), 63));
}

__global__ __launch_bounds__(256) void entmax15_kernel(const float* __restrict__ x,
                                                       float* __restrict__ y,
                                                       int nrows) {
    const int wave = threadIdx.x >> 6;
    const int lane = threadIdx.x & 63;
    const int row  = blockIdx.x * WAVES_PER_BLOCK + wave;
    if (row >= nrows) return;

    const float4* xr = (const float4*)(x + (size_t)row * D);
    float4*       yr = (float4*)(y + (size_t)row * D);

    // Coalesced: lane i takes float4 #(i + 64*j), j = 0..3 -> 1024 floats.
    float4 v4[4];
#pragma unroll
    for (int j = 0; j < 4; ++j) v4[j] = xr[lane + 64 * j];
    float* v = (float*)v4;

    // x <- x/2 ; row max (no subtraction: fold the shift into tau0)
    float m = -3.4e38f;
#pragma unroll
    for (int i = 0; i < 16; ++i) { v[i] *= 0.5f; m = fmaxf(m, v[i]); }
    m = wave_max(m);

    // Newton: f(tau) = sum max(v - tau, 0)^2 ; f' = -2 * sum max(v - tau, 0).
    // tau0 = m - 1: f(tau0) >= (m - tau0)^2 = 1, so we approach the root
    // monotonically from the left (f convex decreasing). s1 > 0 throughout.
    float tau = m - 1.0f;
    for (int it = 0; it < 30; ++it) {
        float s1 = 0.f, s2 = 0.f;
#pragma unroll
        for (int i = 0; i < 16; ++i) {
            float t = fmaxf(v[i] - tau, 0.f);
            s1 += t;
            s2 = fmaf(t, t, s2);
        }
        float S1 = wave_sum(s1);
        float S2 = wave_sum(s2);
        float diff = S2 - 1.0f;       // >= 0 until converged/overshoot
        if (diff <= 1e-6f) break;     // SGPR-uniform -> scalar branch
        tau += diff / (2.0f * S1);
    }

    // y = max(v - tau, 0)^2, coalesced float4 stores.
#pragma unroll
    for (int j = 0; j < 4; ++j) {
        float4 o;
        float t0 = fmaxf(v4[j].x - tau, 0.f); o.x = t0 * t0;
        float t1 = fmaxf(v4[j].y - tau, 0.f); o.y = t1 * t1;
        float t2 = fmaxf(v4[j].z - tau, 0.f); o.z = t2 * t2;
        float t3 = fmaxf(v4[j].w - tau, 0.f); o.w = t3 * t3;
        yr[lane + 64 * j] = o;
    }
}

extern "C" void kernel_launch(void* const* d_in, const int* in_sizes, int n_in,
                              void* d_out, int out_size, void* d_ws, size_t ws_size,
                              hipStream_t stream) {
    const float* x = (const float*)d_in[0];
    float*       y = (float*)d_out;
    const int nrows = in_sizes[0] / D;              // 131072
    const int blocks = (nrows + WAVES_PER_BLOCK - 1) / WAVES_PER_BLOCK;
    entmax15_kernel<<<blocks, 256, 0, stream>>>(x, y, nrows);
}